// Round 3
// baseline (777.315 us; speedup 1.0000x reference)
//
#include <hip/hip_runtime.h>
#include <math.h>

// Problem constants (fixed by setup_inputs)
#define BB 8
#define NN 2048
#define HH 128
#define NSEG 8             // j-segments per node (256 j's each)
#define SEGJ 256
#define SEGCAP 12          // capacity per segment (Poisson mean ~1.1/seg)
#define MAXNBR (NSEG*SEGCAP)  // 96 per node
#define PREDL 10
#define TSTRIDE (NN*3)
#define OUT_BSTRIDE ((PREDL+1)*NN*3)

// R17: revert R16's speculative gather (regressed +2.5%: extra traffic on an
// issue-bound path); restore R15 chunk-4 gathers. NEW: readlane-GEMM in
// k_mid/k_last — u stays in registers after gather (node n's 128 channels
// live in lanes n_local*16+(k>>3), reg k&7 of one wave); wave wv computes
// nodes 4wv..4wv+3, lane owns 2 cols. Per k: 1 ds_read_b64 (W, shared by
// 4 nodes) + 4 v_readlane + 8 fma. LDS issue per 32 fma: 6 -> 1. uS LDS
// array deleted (block LDS 49.4 -> 32 KB); 16 waves/CU preserved (R11
// optimum). All FP ops and per-output k-ascending order unchanged ->
// absmax must stay exactly 0.03125.

__device__ __forceinline__ float rdlane(float v, int l) {
    return __int_as_float(__builtin_amdgcn_readlane(__float_as_int(v), l));
}

// ---------------------------------------------------------------------------
// K0: states0 = [points, 0]; write t=0 output slice
// ---------------------------------------------------------------------------
__global__ __launch_bounds__(256) void k_init(const float* __restrict__ points,
                                              float* __restrict__ states,
                                              float* __restrict__ out) {
    int idx = blockIdx.x * 256 + threadIdx.x;
    if (idx >= BB * NN) return;
    int b = idx >> 11;
    int n = idx & 2047;
    float px = points[idx * 3 + 0];
    float py = points[idx * 3 + 1];
    float pz = points[idx * 3 + 2];
    float* s = states + (size_t)idx * 6;
    s[0] = px; s[1] = py; s[2] = pz; s[3] = 0.f; s[4] = 0.f; s[5] = 0.f;
    float* o = out + (size_t)b * OUT_BSTRIDE + n * 3;
    o[0] = px; o[1] = py; o[2] = pz;
}

// ---------------------------------------------------------------------------
// K1: radius-graph (verbatim, bit-exact verified). 256 blocks x 512 thr;
// wave = one seg x 64 nodes -> pos[j] is ONE LDS address per wave.
// ---------------------------------------------------------------------------
__global__ __launch_bounds__(512, 2) void k_adj(const float* __restrict__ states,
                                                float* __restrict__ xs0,
                                                float* __restrict__ dinv,
                                                int* __restrict__ nbr,
                                                int* __restrict__ cntN) {
    const float R2c = 0.01f;
    int b = blockIdx.x & 7;
    int tile = blockIdx.x >> 3;     // 0..31 (64 nodes each)
    __shared__ float4 pos[NN];                  // 32 KiB
    __shared__ int degs[512];                   // 2 KiB
    __shared__ unsigned short jb[512][SEGCAP];  // 12 KiB
    const float* sb = states + (size_t)b * NN * 6;
    for (int j = threadIdx.x; j < NN; j += 512) {
        const float* r = sb + j * 6;
        pos[j] = make_float4(r[0], r[1], r[2], 0.f);
    }
    __syncthreads();
    int node = threadIdx.x & 63;
    int seg  = threadIdx.x >> 6;     // 0..7 == wave id
    int i = tile * 64 + node;
    int gi = b * NN + i;
    float4 pi = pos[i];
    int cnt = 0;
    int j0 = seg * SEGJ;
#pragma unroll 4
    for (int j = j0; j < j0 + SEGJ; ++j) {
        float4 pj = pos[j];
        float dx = pi.x - pj.x;
        float dy = pi.y - pj.y;
        float dz = pi.z - pj.z;
        // exact np order: (dx*dx + dy*dy) + dz*dz, each op rounded, no fma
        float d2 = __fadd_rn(__fadd_rn(__fmul_rn(dx, dx), __fmul_rn(dy, dy)),
                             __fmul_rn(dz, dz));
        if (d2 < R2c && j != i) {
            if (cnt < SEGCAP) jb[threadIdx.x][cnt] = (unsigned short)j;
            cnt++;
        }
    }
    if (cnt > SEGCAP) cnt = SEGCAP;
    degs[threadIdx.x] = cnt;        // tid == seg*64 + node
    __syncthreads();
    int off = 0;
    for (int s = 0; s < seg; ++s) off += degs[s * 64 + node];
    int base = gi * MAXNBR + off;
    for (int k = 0; k < cnt; ++k) nbr[base + k] = (int)jb[threadIdx.x][k];
    if (seg == NSEG - 1) {
        int tot = off + cnt;
        cntN[gi] = tot;
        float di = (float)(1.0 / sqrt((double)(1 + tot)));  // exact rsqrt
        dinv[gi] = di;
        const float* srow = sb + (size_t)i * 6;
        float* xr = xs0 + (size_t)gi * 6;
#pragma unroll
        for (int c = 0; c < 6; ++c) xr[c] = di * srow[c];
    }
}

// ---------------------------------------------------------------------------
// K2: layer 0 (6 -> 128). 512 blocks x 512 thr: 32 nodes x 16 parts (8 ch).
// R15 chunk-4 gather (conditional loads, k-ascending adds).
// ---------------------------------------------------------------------------
__global__ __launch_bounds__(512, 4) void k_l0(const float* __restrict__ xs0,
                                               const float* __restrict__ dinv,
                                               const int* __restrict__ nbr,
                                               const int* __restrict__ cntN,
                                               const float* __restrict__ W0,
                                               const float* __restrict__ b0,
                                               float* __restrict__ xs1) {
    int b = blockIdx.x & 7;
    int tile = blockIdx.x >> 3;
    int node = threadIdx.x >> 4;   // 0..31
    int part = threadIdx.x & 15;   // 8 ch each
    int i = tile * 32 + node;
    int gi = b * NN + i;
    float g[6];
    {
        const float* sr = xs0 + (size_t)gi * 6;
        float2 a0 = *(const float2*)sr;
        float2 a1 = *(const float2*)(sr + 2);
        float2 a2 = *(const float2*)(sr + 4);
        g[0] = a0.x; g[1] = a0.y; g[2] = a1.x; g[3] = a1.y; g[4] = a2.x; g[5] = a2.y;
    }
    int cnt = cntN[gi];
    const int* nb = nbr + gi * MAXNBR;
    const float* xb = xs0 + (size_t)b * NN * 6;
    int k = 0;
    for (; k + 4 <= cnt; k += 4) {
        const float* r0 = xb + (size_t)nb[k]     * 6;
        const float* r1 = xb + (size_t)nb[k + 1] * 6;
        const float* r2 = xb + (size_t)nb[k + 2] * 6;
        const float* r3 = xb + (size_t)nb[k + 3] * 6;
        float2 v00 = *(const float2*)r0, v01 = *(const float2*)(r0 + 2), v02 = *(const float2*)(r0 + 4);
        float2 v10 = *(const float2*)r1, v11 = *(const float2*)(r1 + 2), v12 = *(const float2*)(r1 + 4);
        float2 v20 = *(const float2*)r2, v21 = *(const float2*)(r2 + 2), v22 = *(const float2*)(r2 + 4);
        float2 v30 = *(const float2*)r3, v31 = *(const float2*)(r3 + 2), v32 = *(const float2*)(r3 + 4);
        g[0] += v00.x; g[1] += v00.y; g[2] += v01.x; g[3] += v01.y; g[4] += v02.x; g[5] += v02.y;
        g[0] += v10.x; g[1] += v10.y; g[2] += v11.x; g[3] += v11.y; g[4] += v12.x; g[5] += v12.y;
        g[0] += v20.x; g[1] += v20.y; g[2] += v21.x; g[3] += v21.y; g[4] += v22.x; g[5] += v22.y;
        g[0] += v30.x; g[1] += v30.y; g[2] += v31.x; g[3] += v31.y; g[4] += v32.x; g[5] += v32.y;
    }
    for (; k < cnt; ++k) {
        int j = nb[k];
        const float* xr = xb + (size_t)j * 6;
        float2 v0 = *(const float2*)xr;
        float2 v1 = *(const float2*)(xr + 2);
        float2 v2 = *(const float2*)(xr + 4);
        g[0] += v0.x; g[1] += v0.y; g[2] += v1.x;
        g[3] += v1.y; g[4] += v2.x; g[5] += v2.y;
    }
    float di = dinv[gi];
#pragma unroll
    for (int c = 0; c < 6; ++c) g[c] *= di;
    int c0 = part * 8;
    float y[8];
#pragma unroll
    for (int r = 0; r < 2; ++r) {
        float4 bv = *(const float4*)(b0 + c0 + r * 4);
        y[r * 4 + 0] = bv.x; y[r * 4 + 1] = bv.y; y[r * 4 + 2] = bv.z; y[r * 4 + 3] = bv.w;
    }
#pragma unroll
    for (int kk = 0; kk < 6; ++kk) {
        float u = g[kk];
        const float* wr = W0 + kk * HH + c0;
#pragma unroll
        for (int r = 0; r < 2; ++r) {
            float4 w = *(const float4*)(wr + r * 4);
            y[r * 4 + 0] = fmaf(u, w.x, y[r * 4 + 0]);
            y[r * 4 + 1] = fmaf(u, w.y, y[r * 4 + 1]);
            y[r * 4 + 2] = fmaf(u, w.z, y[r * 4 + 2]);
            y[r * 4 + 3] = fmaf(u, w.w, y[r * 4 + 3]);
        }
    }
    float* xo = xs1 + (size_t)gi * HH + c0;
#pragma unroll
    for (int r = 0; r < 2; ++r) {
        float4 v;
        v.x = di * fmaxf(y[r * 4 + 0], 0.f);
        v.y = di * fmaxf(y[r * 4 + 1], 0.f);
        v.z = di * fmaxf(y[r * 4 + 2], 0.f);
        v.w = di * fmaxf(y[r * 4 + 3], 0.f);
        *(float4*)(xo + r * 4) = v;
    }
}

// ---------------------------------------------------------------------------
// 128->128 layers: 512 blocks x 512 thr, 16 waves/CU.
// Gather (R15 chunk-4) -> u stays in REGISTERS (lane n_l*16+(k>>3), reg k&7).
// GEMM: wave wv owns nodes 4wv..4wv+3; lane owns cols {2*lane, 2*lane+1};
// per k: 1 ds_read_b64 of W + 4 v_readlane + 8 fma. No uS LDS array.
// ---------------------------------------------------------------------------
__device__ __forceinline__ void gather_to_reg(const float* __restrict__ xin,
                                              const float* __restrict__ dinv,
                                              const int* __restrict__ nbr,
                                              const int* __restrict__ cntN,
                                              int b, int tile, float u[8]) {
    const int node = threadIdx.x >> 4;   // 0..31
    const int part = threadIdx.x & 15;   // 8 ch each
    const int i = tile * 32 + node;
    const int gi = b * NN + i;
    const int c0 = part * 8;
    float acc[8];
    const float* xs = xin + (size_t)gi * HH + c0;
#pragma unroll
    for (int r = 0; r < 2; ++r) *(float4*)&acc[r * 4] = *(const float4*)(xs + r * 4);
    const int cnt = cntN[gi];
    const int* nb = nbr + gi * MAXNBR;
    const float* xb = xin + (size_t)b * NN * HH + c0;
    int k = 0;
    for (; k + 4 <= cnt; k += 4) {
        const float* r0 = xb + (size_t)nb[k]     * HH;
        const float* r1 = xb + (size_t)nb[k + 1] * HH;
        const float* r2 = xb + (size_t)nb[k + 2] * HH;
        const float* r3 = xb + (size_t)nb[k + 3] * HH;
        float4 a0 = *(const float4*)r0, b0 = *(const float4*)(r0 + 4);
        float4 a1 = *(const float4*)r1, b1 = *(const float4*)(r1 + 4);
        float4 a2 = *(const float4*)r2, b2 = *(const float4*)(r2 + 4);
        float4 a3 = *(const float4*)r3, b3 = *(const float4*)(r3 + 4);
        acc[0] += a0.x; acc[1] += a0.y; acc[2] += a0.z; acc[3] += a0.w;
        acc[4] += b0.x; acc[5] += b0.y; acc[6] += b0.z; acc[7] += b0.w;
        acc[0] += a1.x; acc[1] += a1.y; acc[2] += a1.z; acc[3] += a1.w;
        acc[4] += b1.x; acc[5] += b1.y; acc[6] += b1.z; acc[7] += b1.w;
        acc[0] += a2.x; acc[1] += a2.y; acc[2] += a2.z; acc[3] += a2.w;
        acc[4] += b2.x; acc[5] += b2.y; acc[6] += b2.z; acc[7] += b2.w;
        acc[0] += a3.x; acc[1] += a3.y; acc[2] += a3.z; acc[3] += a3.w;
        acc[4] += b3.x; acc[5] += b3.y; acc[6] += b3.z; acc[7] += b3.w;
    }
    for (; k < cnt; ++k) {
        const int j = nb[k];
        const float* xr = xb + (size_t)j * HH;
#pragma unroll
        for (int r = 0; r < 2; ++r) {
            float v[4];
            *(float4*)v = *(const float4*)(xr + r * 4);
            acc[r * 4 + 0] += v[0]; acc[r * 4 + 1] += v[1];
            acc[r * 4 + 2] += v[2]; acc[r * 4 + 3] += v[3];
        }
    }
    const float di = dinv[gi];
#pragma unroll
    for (int e = 0; e < 8; ++e) u[e] = acc[e] * di;   // same rn(di*acc) as uS store
}

// K3: middle layer (layer 1): xs_out = dinv * relu(u @ W + b)
__global__ __launch_bounds__(512, 4) void k_mid(const float* __restrict__ xin,
                                                const float* __restrict__ dinv,
                                                const int* __restrict__ nbr,
                                                const int* __restrict__ cntN,
                                                const float* __restrict__ W,
                                                const float* __restrict__ bias,
                                                float* __restrict__ xout) {
    __shared__ __align__(16) float wS[2][32 * HH];   // 32 KB (uS deleted)
    int b = blockIdx.x & 7;
    int tile = blockIdx.x >> 3;
    int t = threadIdx.x;
    const float4* Wf4 = (const float4*)W;
    float4 wreg[2];
    wreg[0] = Wf4[t]; wreg[1] = Wf4[t + 512];   // panel 0
    float u[8];
    gather_to_reg(xin, dinv, nbr, cntN, b, tile, u);
    {
        float4* ws4 = (float4*)wS[0];
        ws4[t] = wreg[0]; ws4[t + 512] = wreg[1];
    }
    __syncthreads();
    const int lane = t & 63;
    const int wv = t >> 6;           // wave id 0..7 -> nodes 4wv..4wv+3
    float y[8];
    {
        float2 bv = *(const float2*)(bias + lane * 2);
        y[0] = bv.x; y[1] = bv.y; y[2] = bv.x; y[3] = bv.y;
        y[4] = bv.x; y[5] = bv.y; y[6] = bv.x; y[7] = bv.y;
    }
#pragma unroll
    for (int p = 0; p < 4; ++p) {
        if (p < 3) {
            wreg[0] = Wf4[(p + 1) * 1024 + t];
            wreg[1] = Wf4[(p + 1) * 1024 + t + 512];
        }
        const float* wbuf = wS[p & 1];
#pragma unroll
        for (int r = 0; r < 32; ++r) {
            float2 w = *(const float2*)(wbuf + r * HH + lane * 2);
#pragma unroll
            for (int n = 0; n < 4; ++n) {
                float s = rdlane(u[r & 7], n * 16 + p * 4 + (r >> 3));
                y[n * 2 + 0] = fmaf(s, w.x, y[n * 2 + 0]);
                y[n * 2 + 1] = fmaf(s, w.y, y[n * 2 + 1]);
            }
        }
        if (p < 3) {
            float4* ws4 = (float4*)wS[1 - (p & 1)];
            ws4[t] = wreg[0]; ws4[t + 512] = wreg[1];
            __syncthreads();
        }
    }
    const int gbase = b * NN + tile * 32 + wv * 4;
#pragma unroll
    for (int n = 0; n < 4; ++n) {
        float dv = dinv[gbase + n];          // wave-uniform -> s_load
        float2 o;
        o.x = dv * fmaxf(y[n * 2 + 0], 0.f);
        o.y = dv * fmaxf(y[n * 2 + 1], 0.f);
        *(float2*)(xout + (size_t)(gbase + n) * HH + lane * 2) = o;
    }
}

// K4: layer 2 + FC head + state update + output write.
// After the last panel, wS[0] is reused as y3[32][128] and wS[1] as wfcS.
__global__ __launch_bounds__(512, 4) void k_last(const float* __restrict__ xin,
                                                 const float* __restrict__ dinv,
                                                 const int* __restrict__ nbr,
                                                 const int* __restrict__ cntN,
                                                 const float* __restrict__ W2,
                                                 const float* __restrict__ b2,
                                                 const float* __restrict__ Wfc,
                                                 const float* __restrict__ bfc,
                                                 const float* __restrict__ padding,
                                                 float* __restrict__ states,
                                                 float* __restrict__ outt) {
    __shared__ __align__(16) float wS[2][32 * HH];   // 32 KB
    int b = blockIdx.x & 7;
    int tile = blockIdx.x >> 3;
    int t = threadIdx.x;
    const float4* Wf4 = (const float4*)W2;
    float4 wreg[2];
    wreg[0] = Wf4[t]; wreg[1] = Wf4[t + 512];
    float u[8];
    gather_to_reg(xin, dinv, nbr, cntN, b, tile, u);
    {
        float4* ws4 = (float4*)wS[0];
        ws4[t] = wreg[0]; ws4[t + 512] = wreg[1];
    }
    __syncthreads();
    const int lane = t & 63;
    const int wv = t >> 6;
    float y[8];
    {
        float2 bv = *(const float2*)(b2 + lane * 2);
        y[0] = bv.x; y[1] = bv.y; y[2] = bv.x; y[3] = bv.y;
        y[4] = bv.x; y[5] = bv.y; y[6] = bv.x; y[7] = bv.y;
    }
#pragma unroll
    for (int p = 0; p < 4; ++p) {
        if (p < 3) {
            wreg[0] = Wf4[(p + 1) * 1024 + t];
            wreg[1] = Wf4[(p + 1) * 1024 + t + 512];
        }
        const float* wbuf = wS[p & 1];
#pragma unroll
        for (int r = 0; r < 32; ++r) {
            float2 w = *(const float2*)(wbuf + r * HH + lane * 2);
#pragma unroll
            for (int n = 0; n < 4; ++n) {
                float s = rdlane(u[r & 7], n * 16 + p * 4 + (r >> 3));
                y[n * 2 + 0] = fmaf(s, w.x, y[n * 2 + 0]);
                y[n * 2 + 1] = fmaf(s, w.y, y[n * 2 + 1]);
            }
        }
        if (p < 3) {
            float4* ws4 = (float4*)wS[1 - (p & 1)];
            ws4[t] = wreg[0]; ws4[t + 512] = wreg[1];
            __syncthreads();
        }
    }
    __syncthreads();   // all panel reads done; reuse wS
    float* y3  = wS[0];   // [32][HH]
    float* wfc = wS[1];   // HH*6 floats
    for (int q = t; q < HH * 6; q += 512) wfc[q] = Wfc[q];
#pragma unroll
    for (int n = 0; n < 4; ++n) {
        float2 v;
        v.x = fmaxf(y[n * 2 + 0], 0.f);
        v.y = fmaxf(y[n * 2 + 1], 0.f);
        *(float2*)&y3[(wv * 4 + n) * HH + lane * 2] = v;
    }
    __syncthreads();
    if (t < 192) {
        int n = t / 6;
        int c = t - n * 6;
        float r = bfc[c];
        for (int k = 0; k < HH; k += 4) {
            float yv[4];
            *(float4*)yv = *(const float4*)&y3[n * HH + k];
            r = fmaf(yv[0], wfc[(k + 0) * 6 + c], r);
            r = fmaf(yv[1], wfc[(k + 1) * 6 + c], r);
            r = fmaf(yv[2], wfc[(k + 2) * 6 + c], r);
            r = fmaf(yv[3], wfc[(k + 3) * 6 + c], r);
        }
        int i = tile * 32 + n;
        int gi = b * NN + i;
        float pv = padding[b * NN + i];   // all-ones in this setup
        float s = states[(size_t)gi * 6 + c] + r * pv;
        states[(size_t)gi * 6 + c] = s;
        if (c < 3) outt[(size_t)b * OUT_BSTRIDE + i * 3 + c] = s;
    }
}

// ---------------------------------------------------------------------------
extern "C" void kernel_launch(void* const* d_in, const int* in_sizes, int n_in,
                              void* d_out, int out_size, void* d_ws, size_t ws_size,
                              hipStream_t stream) {
    (void)in_sizes; (void)n_in; (void)out_size; (void)ws_size;
    const float* points  = (const float*)d_in[0];
    const float* padding = (const float*)d_in[5];
    const float* W0  = (const float*)d_in[6];
    const float* b0  = (const float*)d_in[7];
    const float* W1  = (const float*)d_in[8];
    const float* b1  = (const float*)d_in[9];
    const float* W2  = (const float*)d_in[10];
    const float* b2  = (const float*)d_in[11];
    const float* Wfc = (const float*)d_in[12];
    const float* bfc = (const float*)d_in[13];
    float* out = (float*)d_out;

    // workspace carve-up (~24 MB)
    float* ws     = (float*)d_ws;
    float* states = ws;                       // BB*NN*6
    float* xs0    = states + BB * NN * 6;     // BB*NN*6
    float* xs1    = xs0 + BB * NN * 6;        // BB*NN*HH
    float* xs2    = xs1 + BB * NN * HH;       // BB*NN*HH
    float* dinvp  = xs2 + BB * NN * HH;       // BB*NN
    int*   nbr    = (int*)(dinvp + BB * NN);  // BB*NN*MAXNBR
    int*   cntN   = nbr + BB * NN * MAXNBR;   // BB*NN

    k_init<<<(BB * NN) / 256, 256, 0, stream>>>(points, states, out);
    for (int t = 0; t < PREDL; ++t) {
        k_adj<<<256, 512, 0, stream>>>(states, xs0, dinvp, nbr, cntN);
        k_l0<<<512, 512, 0, stream>>>(xs0, dinvp, nbr, cntN, W0, b0, xs1);
        k_mid<<<512, 512, 0, stream>>>(xs1, dinvp, nbr, cntN, W1, b1, xs2);
        k_last<<<512, 512, 0, stream>>>(xs2, dinvp, nbr, cntN, W2, b2, Wfc, bfc,
                                        padding, states,
                                        out + (size_t)(t + 1) * TSTRIDE);
    }
}

// Round 4
// 690.397 us; speedup vs baseline: 1.1259x; 1.1259x over previous
//
#include <hip/hip_runtime.h>
#include <math.h>

// Problem constants (fixed by setup_inputs)
#define BB 8
#define NN 2048
#define HH 128
#define NSEG 8             // j-segments per node (256 j's each)
#define SEGJ 256
#define SEGCAP 12          // capacity per segment (Poisson mean ~1.1/seg)
#define MAXNBR (NSEG*SEGCAP)  // 96 per node
#define PREDL 10
#define TSTRIDE (NN*3)
#define OUT_BSTRIDE ((PREDL+1)*NN*3)

// R18 = R15 base (best, 693 us) + 4-node x 4-col GEMM mapping in k_mid/k_last.
// R16 (speculative gather, +2.5%) and R17 (readlane GEMM, +12%) both reverted.
// R17 lesson: readlane inflated VALU 50% and b64 reads 4-way-conflicted.
// R18 keeps b128 reads and constant VALU: 256 threads x 16 outs (4n x 4c);
// per 64 fma: 4 uS b128 (2 uniq addr/wave, broadcast) + 4 W b128 (512B uniq)
// = 8 LDS instr vs 12 for 2n4c. Threads 256..511 idle during GEMM (park at
// barrier); gather/staging still uses all 512. All fmaf chains k-ascending,
// identical operands -> absmax must stay exactly 0.03125.

// ---------------------------------------------------------------------------
// K0: states0 = [points, 0]; write t=0 output slice
// ---------------------------------------------------------------------------
__global__ __launch_bounds__(256) void k_init(const float* __restrict__ points,
                                              float* __restrict__ states,
                                              float* __restrict__ out) {
    int idx = blockIdx.x * 256 + threadIdx.x;
    if (idx >= BB * NN) return;
    int b = idx >> 11;
    int n = idx & 2047;
    float px = points[idx * 3 + 0];
    float py = points[idx * 3 + 1];
    float pz = points[idx * 3 + 2];
    float* s = states + (size_t)idx * 6;
    s[0] = px; s[1] = py; s[2] = pz; s[3] = 0.f; s[4] = 0.f; s[5] = 0.f;
    float* o = out + (size_t)b * OUT_BSTRIDE + n * 3;
    o[0] = px; o[1] = py; o[2] = pz;
}

// ---------------------------------------------------------------------------
// K1: radius-graph (verbatim, bit-exact verified). 256 blocks x 512 thr;
// wave = one seg x 64 nodes -> pos[j] is ONE LDS address per wave.
// ---------------------------------------------------------------------------
__global__ __launch_bounds__(512, 2) void k_adj(const float* __restrict__ states,
                                                float* __restrict__ xs0,
                                                float* __restrict__ dinv,
                                                int* __restrict__ nbr,
                                                int* __restrict__ cntN) {
    const float R2c = 0.01f;
    int b = blockIdx.x & 7;
    int tile = blockIdx.x >> 3;     // 0..31 (64 nodes each)
    __shared__ float4 pos[NN];                  // 32 KiB
    __shared__ int degs[512];                   // 2 KiB
    __shared__ unsigned short jb[512][SEGCAP];  // 12 KiB
    const float* sb = states + (size_t)b * NN * 6;
    for (int j = threadIdx.x; j < NN; j += 512) {
        const float* r = sb + j * 6;
        pos[j] = make_float4(r[0], r[1], r[2], 0.f);
    }
    __syncthreads();
    int node = threadIdx.x & 63;
    int seg  = threadIdx.x >> 6;     // 0..7 == wave id
    int i = tile * 64 + node;
    int gi = b * NN + i;
    float4 pi = pos[i];
    int cnt = 0;
    int j0 = seg * SEGJ;
#pragma unroll 4
    for (int j = j0; j < j0 + SEGJ; ++j) {
        float4 pj = pos[j];
        float dx = pi.x - pj.x;
        float dy = pi.y - pj.y;
        float dz = pi.z - pj.z;
        // exact np order: (dx*dx + dy*dy) + dz*dz, each op rounded, no fma
        float d2 = __fadd_rn(__fadd_rn(__fmul_rn(dx, dx), __fmul_rn(dy, dy)),
                             __fmul_rn(dz, dz));
        if (d2 < R2c && j != i) {
            if (cnt < SEGCAP) jb[threadIdx.x][cnt] = (unsigned short)j;
            cnt++;
        }
    }
    if (cnt > SEGCAP) cnt = SEGCAP;
    degs[threadIdx.x] = cnt;        // tid == seg*64 + node
    __syncthreads();
    int off = 0;
    for (int s = 0; s < seg; ++s) off += degs[s * 64 + node];
    int base = gi * MAXNBR + off;
    for (int k = 0; k < cnt; ++k) nbr[base + k] = (int)jb[threadIdx.x][k];
    if (seg == NSEG - 1) {
        int tot = off + cnt;
        cntN[gi] = tot;
        float di = (float)(1.0 / sqrt((double)(1 + tot)));  // exact rsqrt
        dinv[gi] = di;
        const float* srow = sb + (size_t)i * 6;
        float* xr = xs0 + (size_t)gi * 6;
#pragma unroll
        for (int c = 0; c < 6; ++c) xr[c] = di * srow[c];
    }
}

// ---------------------------------------------------------------------------
// K2: layer 0 (6 -> 128). 512 blocks x 512 thr: 32 nodes x 16 parts (8 ch).
// R15 chunk-4 gather (conditional loads, k-ascending adds). Verbatim R15.
// ---------------------------------------------------------------------------
__global__ __launch_bounds__(512, 4) void k_l0(const float* __restrict__ xs0,
                                               const float* __restrict__ dinv,
                                               const int* __restrict__ nbr,
                                               const int* __restrict__ cntN,
                                               const float* __restrict__ W0,
                                               const float* __restrict__ b0,
                                               float* __restrict__ xs1) {
    int b = blockIdx.x & 7;
    int tile = blockIdx.x >> 3;
    int node = threadIdx.x >> 4;   // 0..31
    int part = threadIdx.x & 15;   // 8 ch each
    int i = tile * 32 + node;
    int gi = b * NN + i;
    float g[6];
    {
        const float* sr = xs0 + (size_t)gi * 6;
        float2 a0 = *(const float2*)sr;
        float2 a1 = *(const float2*)(sr + 2);
        float2 a2 = *(const float2*)(sr + 4);
        g[0] = a0.x; g[1] = a0.y; g[2] = a1.x; g[3] = a1.y; g[4] = a2.x; g[5] = a2.y;
    }
    int cnt = cntN[gi];
    const int* nb = nbr + gi * MAXNBR;
    const float* xb = xs0 + (size_t)b * NN * 6;
    int k = 0;
    for (; k + 4 <= cnt; k += 4) {
        const float* r0 = xb + (size_t)nb[k]     * 6;
        const float* r1 = xb + (size_t)nb[k + 1] * 6;
        const float* r2 = xb + (size_t)nb[k + 2] * 6;
        const float* r3 = xb + (size_t)nb[k + 3] * 6;
        float2 v00 = *(const float2*)r0, v01 = *(const float2*)(r0 + 2), v02 = *(const float2*)(r0 + 4);
        float2 v10 = *(const float2*)r1, v11 = *(const float2*)(r1 + 2), v12 = *(const float2*)(r1 + 4);
        float2 v20 = *(const float2*)r2, v21 = *(const float2*)(r2 + 2), v22 = *(const float2*)(r2 + 4);
        float2 v30 = *(const float2*)r3, v31 = *(const float2*)(r3 + 2), v32 = *(const float2*)(r3 + 4);
        g[0] += v00.x; g[1] += v00.y; g[2] += v01.x; g[3] += v01.y; g[4] += v02.x; g[5] += v02.y;
        g[0] += v10.x; g[1] += v10.y; g[2] += v11.x; g[3] += v11.y; g[4] += v12.x; g[5] += v12.y;
        g[0] += v20.x; g[1] += v20.y; g[2] += v21.x; g[3] += v21.y; g[4] += v22.x; g[5] += v22.y;
        g[0] += v30.x; g[1] += v30.y; g[2] += v31.x; g[3] += v31.y; g[4] += v32.x; g[5] += v32.y;
    }
    for (; k < cnt; ++k) {
        int j = nb[k];
        const float* xr = xb + (size_t)j * 6;
        float2 v0 = *(const float2*)xr;
        float2 v1 = *(const float2*)(xr + 2);
        float2 v2 = *(const float2*)(xr + 4);
        g[0] += v0.x; g[1] += v0.y; g[2] += v1.x;
        g[3] += v1.y; g[4] += v2.x; g[5] += v2.y;
    }
    float di = dinv[gi];
#pragma unroll
    for (int c = 0; c < 6; ++c) g[c] *= di;
    int c0 = part * 8;
    float y[8];
#pragma unroll
    for (int r = 0; r < 2; ++r) {
        float4 bv = *(const float4*)(b0 + c0 + r * 4);
        y[r * 4 + 0] = bv.x; y[r * 4 + 1] = bv.y; y[r * 4 + 2] = bv.z; y[r * 4 + 3] = bv.w;
    }
#pragma unroll
    for (int kk = 0; kk < 6; ++kk) {
        float u = g[kk];
        const float* wr = W0 + kk * HH + c0;
#pragma unroll
        for (int r = 0; r < 2; ++r) {
            float4 w = *(const float4*)(wr + r * 4);
            y[r * 4 + 0] = fmaf(u, w.x, y[r * 4 + 0]);
            y[r * 4 + 1] = fmaf(u, w.y, y[r * 4 + 1]);
            y[r * 4 + 2] = fmaf(u, w.z, y[r * 4 + 2]);
            y[r * 4 + 3] = fmaf(u, w.w, y[r * 4 + 3]);
        }
    }
    float* xo = xs1 + (size_t)gi * HH + c0;
#pragma unroll
    for (int r = 0; r < 2; ++r) {
        float4 v;
        v.x = di * fmaxf(y[r * 4 + 0], 0.f);
        v.y = di * fmaxf(y[r * 4 + 1], 0.f);
        v.z = di * fmaxf(y[r * 4 + 2], 0.f);
        v.w = di * fmaxf(y[r * 4 + 3], 0.f);
        *(float4*)(xo + r * 4) = v;
    }
}

// ---------------------------------------------------------------------------
// 128->128 layers: 512 blocks x 512 thr, 32-node tiles, 16 waves/CU.
// Gather (R15 chunk-4, all 512 threads) -> uS. GEMM: 256 threads, each owns
// 4 nodes x 4 cols; per 32-row panel r-step: 4 uS b128 (2 uniq addr/wave)
// + 4 W b128 (512B uniq) + 64 fma. W LDS panels double-buffered.
// ---------------------------------------------------------------------------
__device__ __forceinline__ void gather_into_lds(const float* __restrict__ xin,
                                                const float* __restrict__ dinv,
                                                const int* __restrict__ nbr,
                                                const int* __restrict__ cntN,
                                                int b, int tile,
                                                float (*uS)[HH + 4]) {
    const int node = threadIdx.x >> 4;   // 0..31
    const int part = threadIdx.x & 15;   // 8 ch each
    const int i = tile * 32 + node;
    const int gi = b * NN + i;
    const int c0 = part * 8;
    float acc[8];
    const float* xs = xin + (size_t)gi * HH + c0;
#pragma unroll
    for (int r = 0; r < 2; ++r) *(float4*)&acc[r * 4] = *(const float4*)(xs + r * 4);
    const int cnt = cntN[gi];
    const int* nb = nbr + gi * MAXNBR;
    const float* xb = xin + (size_t)b * NN * HH + c0;
    int k = 0;
    for (; k + 4 <= cnt; k += 4) {
        const float* r0 = xb + (size_t)nb[k]     * HH;
        const float* r1 = xb + (size_t)nb[k + 1] * HH;
        const float* r2 = xb + (size_t)nb[k + 2] * HH;
        const float* r3 = xb + (size_t)nb[k + 3] * HH;
        float4 a0 = *(const float4*)r0, b0 = *(const float4*)(r0 + 4);
        float4 a1 = *(const float4*)r1, b1 = *(const float4*)(r1 + 4);
        float4 a2 = *(const float4*)r2, b2 = *(const float4*)(r2 + 4);
        float4 a3 = *(const float4*)r3, b3 = *(const float4*)(r3 + 4);
        acc[0] += a0.x; acc[1] += a0.y; acc[2] += a0.z; acc[3] += a0.w;
        acc[4] += b0.x; acc[5] += b0.y; acc[6] += b0.z; acc[7] += b0.w;
        acc[0] += a1.x; acc[1] += a1.y; acc[2] += a1.z; acc[3] += a1.w;
        acc[4] += b1.x; acc[5] += b1.y; acc[6] += b1.z; acc[7] += b1.w;
        acc[0] += a2.x; acc[1] += a2.y; acc[2] += a2.z; acc[3] += a2.w;
        acc[4] += b2.x; acc[5] += b2.y; acc[6] += b2.z; acc[7] += b2.w;
        acc[0] += a3.x; acc[1] += a3.y; acc[2] += a3.z; acc[3] += a3.w;
        acc[4] += b3.x; acc[5] += b3.y; acc[6] += b3.z; acc[7] += b3.w;
    }
    for (; k < cnt; ++k) {
        const int j = nb[k];
        const float* xr = xb + (size_t)j * HH;
#pragma unroll
        for (int r = 0; r < 2; ++r) {
            float v[4];
            *(float4*)v = *(const float4*)(xr + r * 4);
            acc[r * 4 + 0] += v[0]; acc[r * 4 + 1] += v[1];
            acc[r * 4 + 2] += v[2]; acc[r * 4 + 3] += v[3];
        }
    }
    const float di = dinv[gi];
#pragma unroll
    for (int r = 0; r < 2; ++r) {
        float4 o;
        o.x = acc[r * 4 + 0] * di; o.y = acc[r * 4 + 1] * di;
        o.z = acc[r * 4 + 2] * di; o.w = acc[r * 4 + 3] * di;
        *(float4*)&uS[node][c0 + r * 4] = o;
    }
}

// GEMM over one 32-row W panel in LDS. Thread owns 4 nodes x 4 channels;
// one W float4 feeds all 4 nodes, one uS b128 covers 4 k's of one node.
// Per-output k-ascending fmaf order -> bit-identical to 2n4c / 1n8c.
__device__ __forceinline__ void gemm_panel4(const float (*uS)[HH + 4],
                                            const float* __restrict__ wbuf,
                                            int p, int nbase, int cA,
                                            float y[16]) {
#pragma unroll
    for (int r = 0; r < 32; r += 4) {
        float ua[16];
        *(float4*)&ua[0]  = *(const float4*)(&uS[nbase + 0][p * 32 + r]);
        *(float4*)&ua[4]  = *(const float4*)(&uS[nbase + 1][p * 32 + r]);
        *(float4*)&ua[8]  = *(const float4*)(&uS[nbase + 2][p * 32 + r]);
        *(float4*)&ua[12] = *(const float4*)(&uS[nbase + 3][p * 32 + r]);
        const float* wrow = wbuf + r * HH + cA;
#pragma unroll
        for (int q = 0; q < 4; ++q) {
            float4 w = *(const float4*)(wrow + q * HH);
#pragma unroll
            for (int n = 0; n < 4; ++n) {
                float uq = ua[n * 4 + q];
                y[n * 4 + 0] = fmaf(uq, w.x, y[n * 4 + 0]);
                y[n * 4 + 1] = fmaf(uq, w.y, y[n * 4 + 1]);
                y[n * 4 + 2] = fmaf(uq, w.z, y[n * 4 + 2]);
                y[n * 4 + 3] = fmaf(uq, w.w, y[n * 4 + 3]);
            }
        }
    }
}

// K3: middle layer (layer 1): xs_out = dinv * relu(u @ W + b)
__global__ __launch_bounds__(512, 4) void k_mid(const float* __restrict__ xin,
                                                const float* __restrict__ dinv,
                                                const int* __restrict__ nbr,
                                                const int* __restrict__ cntN,
                                                const float* __restrict__ W,
                                                const float* __restrict__ bias,
                                                float* __restrict__ xout) {
    __shared__ __align__(16) float uS[32][HH + 4];   // 16.9 KB
    __shared__ __align__(16) float wS[2][32 * HH];   // 32 KB
    int b = blockIdx.x & 7;
    int tile = blockIdx.x >> 3;
    int t = threadIdx.x;
    const float4* Wf4 = (const float4*)W;
    float4 wreg[2];
    wreg[0] = Wf4[t]; wreg[1] = Wf4[t + 512];   // panel 0
    gather_into_lds(xin, dinv, nbr, cntN, b, tile, uS);
    {
        float4* ws4 = (float4*)wS[0];
        ws4[t] = wreg[0]; ws4[t + 512] = wreg[1];
    }
    __syncthreads();
    const int cq = t & 31, nq = t >> 5;   // nq 0..15; GEMM active for nq<8
    const int cA = cq * 4;
    const int nbase = (nq & 7) * 4;
    const bool act = (nq < 8);
    float y[16];
    if (act) {
        float4 bv = *(const float4*)(bias + cA);
#pragma unroll
        for (int n = 0; n < 4; ++n) {
            y[n * 4 + 0] = bv.x; y[n * 4 + 1] = bv.y;
            y[n * 4 + 2] = bv.z; y[n * 4 + 3] = bv.w;
        }
    }
#pragma unroll
    for (int p = 0; p < 4; ++p) {
        if (p < 3) {
            wreg[0] = Wf4[(p + 1) * 1024 + t];
            wreg[1] = Wf4[(p + 1) * 1024 + t + 512];
        }
        if (act) gemm_panel4(uS, wS[p & 1], p, nbase, cA, y);
        if (p < 3) {
            float4* ws4 = (float4*)wS[1 - (p & 1)];
            ws4[t] = wreg[0]; ws4[t + 512] = wreg[1];
            __syncthreads();
        }
    }
    if (act) {
        const int gbase = b * NN + tile * 32 + nbase;
#pragma unroll
        for (int n = 0; n < 4; ++n) {
            float dv = dinv[gbase + n];
            float4 o;
            o.x = dv * fmaxf(y[n * 4 + 0], 0.f);
            o.y = dv * fmaxf(y[n * 4 + 1], 0.f);
            o.z = dv * fmaxf(y[n * 4 + 2], 0.f);
            o.w = dv * fmaxf(y[n * 4 + 3], 0.f);
            *(float4*)(xout + (size_t)(gbase + n) * HH + cA) = o;
        }
    }
}

// K4: layer 2 + FC head + state update + output write.
// After the last panel, wS[0] is reused as y3[32][128] and wS[1] as wfcS.
__global__ __launch_bounds__(512, 4) void k_last(const float* __restrict__ xin,
                                                 const float* __restrict__ dinv,
                                                 const int* __restrict__ nbr,
                                                 const int* __restrict__ cntN,
                                                 const float* __restrict__ W2,
                                                 const float* __restrict__ b2,
                                                 const float* __restrict__ Wfc,
                                                 const float* __restrict__ bfc,
                                                 const float* __restrict__ padding,
                                                 float* __restrict__ states,
                                                 float* __restrict__ outt) {
    __shared__ __align__(16) float uS[32][HH + 4];   // 16.9 KB
    __shared__ __align__(16) float wS[2][32 * HH];   // 32 KB
    int b = blockIdx.x & 7;
    int tile = blockIdx.x >> 3;
    int t = threadIdx.x;
    const float4* Wf4 = (const float4*)W2;
    float4 wreg[2];
    wreg[0] = Wf4[t]; wreg[1] = Wf4[t + 512];
    gather_into_lds(xin, dinv, nbr, cntN, b, tile, uS);
    {
        float4* ws4 = (float4*)wS[0];
        ws4[t] = wreg[0]; ws4[t + 512] = wreg[1];
    }
    __syncthreads();
    const int cq = t & 31, nq = t >> 5;
    const int cA = cq * 4;
    const int nbase = (nq & 7) * 4;
    const bool act = (nq < 8);
    float y[16];
    if (act) {
        float4 bv = *(const float4*)(b2 + cA);
#pragma unroll
        for (int n = 0; n < 4; ++n) {
            y[n * 4 + 0] = bv.x; y[n * 4 + 1] = bv.y;
            y[n * 4 + 2] = bv.z; y[n * 4 + 3] = bv.w;
        }
    }
#pragma unroll
    for (int p = 0; p < 4; ++p) {
        if (p < 3) {
            wreg[0] = Wf4[(p + 1) * 1024 + t];
            wreg[1] = Wf4[(p + 1) * 1024 + t + 512];
        }
        if (act) gemm_panel4(uS, wS[p & 1], p, nbase, cA, y);
        if (p < 3) {
            float4* ws4 = (float4*)wS[1 - (p & 1)];
            ws4[t] = wreg[0]; ws4[t + 512] = wreg[1];
            __syncthreads();
        }
    }
    __syncthreads();   // all panel reads done; reuse wS
    float* y3  = wS[0];   // [32][HH]
    float* wfc = wS[1];   // HH*6 floats
    for (int q = t; q < HH * 6; q += 512) wfc[q] = Wfc[q];
    if (act) {
#pragma unroll
        for (int n = 0; n < 4; ++n) {
            float4 v;
            v.x = fmaxf(y[n * 4 + 0], 0.f);
            v.y = fmaxf(y[n * 4 + 1], 0.f);
            v.z = fmaxf(y[n * 4 + 2], 0.f);
            v.w = fmaxf(y[n * 4 + 3], 0.f);
            *(float4*)&y3[(nbase + n) * HH + cA] = v;
        }
    }
    __syncthreads();
    if (t < 192) {
        int n = t / 6;
        int c = t - n * 6;
        float r = bfc[c];
        for (int k = 0; k < HH; k += 4) {
            float yv[4];
            *(float4*)yv = *(const float4*)&y3[n * HH + k];
            r = fmaf(yv[0], wfc[(k + 0) * 6 + c], r);
            r = fmaf(yv[1], wfc[(k + 1) * 6 + c], r);
            r = fmaf(yv[2], wfc[(k + 2) * 6 + c], r);
            r = fmaf(yv[3], wfc[(k + 3) * 6 + c], r);
        }
        int i = tile * 32 + n;
        int gi = b * NN + i;
        float pv = padding[b * NN + i];   // all-ones in this setup
        float s = states[(size_t)gi * 6 + c] + r * pv;
        states[(size_t)gi * 6 + c] = s;
        if (c < 3) outt[(size_t)b * OUT_BSTRIDE + i * 3 + c] = s;
    }
}

// ---------------------------------------------------------------------------
extern "C" void kernel_launch(void* const* d_in, const int* in_sizes, int n_in,
                              void* d_out, int out_size, void* d_ws, size_t ws_size,
                              hipStream_t stream) {
    (void)in_sizes; (void)n_in; (void)out_size; (void)ws_size;
    const float* points  = (const float*)d_in[0];
    const float* padding = (const float*)d_in[5];
    const float* W0  = (const float*)d_in[6];
    const float* b0  = (const float*)d_in[7];
    const float* W1  = (const float*)d_in[8];
    const float* b1  = (const float*)d_in[9];
    const float* W2  = (const float*)d_in[10];
    const float* b2  = (const float*)d_in[11];
    const float* Wfc = (const float*)d_in[12];
    const float* bfc = (const float*)d_in[13];
    float* out = (float*)d_out;

    // workspace carve-up (~24 MB)
    float* ws     = (float*)d_ws;
    float* states = ws;                       // BB*NN*6
    float* xs0    = states + BB * NN * 6;     // BB*NN*6
    float* xs1    = xs0 + BB * NN * 6;        // BB*NN*HH
    float* xs2    = xs1 + BB * NN * HH;       // BB*NN*HH
    float* dinvp  = xs2 + BB * NN * HH;       // BB*NN
    int*   nbr    = (int*)(dinvp + BB * NN);  // BB*NN*MAXNBR
    int*   cntN   = nbr + BB * NN * MAXNBR;   // BB*NN

    k_init<<<(BB * NN) / 256, 256, 0, stream>>>(points, states, out);
    for (int t = 0; t < PREDL; ++t) {
        k_adj<<<256, 512, 0, stream>>>(states, xs0, dinvp, nbr, cntN);
        k_l0<<<512, 512, 0, stream>>>(xs0, dinvp, nbr, cntN, W0, b0, xs1);
        k_mid<<<512, 512, 0, stream>>>(xs1, dinvp, nbr, cntN, W1, b1, xs2);
        k_last<<<512, 512, 0, stream>>>(xs2, dinvp, nbr, cntN, W2, b2, Wfc, bfc,
                                        padding, states,
                                        out + (size_t)(t + 1) * TSTRIDE);
    }
}

// Round 5
// 656.656 us; speedup vs baseline: 1.1837x; 1.0514x over previous
//
#include <hip/hip_runtime.h>
#include <math.h>

// Problem constants (fixed by setup_inputs)
#define BB 8
#define NN 2048
#define HH 128
#define NSEG 16            // j-segments per node (128 j's each)  [R19: was 8x256]
#define SEGJ 128
#define SEGCAP 6           // capacity per segment (Poisson mean ~0.54/seg)
#define MAXNBR (NSEG*SEGCAP)  // 96 per node — slab size unchanged
#define PREDL 10
#define TSTRIDE (NN*3)
#define OUT_BSTRIDE ((PREDL+1)*NN*3)

// R19 = R18 (best, 690 us) + k_adj 2-nodes-per-thread re-partition.
// k_adj was the last unexamined kernel: 2048 broadcast ds_read_b128/block
// (~LDS-pipe-bound) vs ~4.3 us VALU. Each thread now owns a node PAIR
// (pair, pair+32) and one 128-j seg: each pos[j] LDS read feeds 2 pair
// computes -> LDS instrs halved, VALU unchanged, same blocks/occupancy.
// Per-wave: lanes span 2 segs -> 2 broadcast addrs/read (free, 2-way).
// d2 expression per (i,j) identical, computed exactly once; nbr list stays
// seg-major = j-ascending; dinv/xs0 verbatim -> bit-identical.
// SEGCAP 6@128j keeps MAXNBR=96 (workspace layout unchanged), same ~11x
// margin over Poisson mean as 12@256j. absmax must stay exactly 0.03125.
// Falsified so far: speculative gather (R16 +2.5%), readlane GEMM (R17
// +12%), GEMM LDS cuts beyond R15 (R18 neutral), grid-sync/fusion/occupancy
// changes (previous session R4/R5/R8/R9/R13).

// ---------------------------------------------------------------------------
// K0: states0 = [points, 0]; write t=0 output slice
// ---------------------------------------------------------------------------
__global__ __launch_bounds__(256) void k_init(const float* __restrict__ points,
                                              float* __restrict__ states,
                                              float* __restrict__ out) {
    int idx = blockIdx.x * 256 + threadIdx.x;
    if (idx >= BB * NN) return;
    int b = idx >> 11;
    int n = idx & 2047;
    float px = points[idx * 3 + 0];
    float py = points[idx * 3 + 1];
    float pz = points[idx * 3 + 2];
    float* s = states + (size_t)idx * 6;
    s[0] = px; s[1] = py; s[2] = pz; s[3] = 0.f; s[4] = 0.f; s[5] = 0.f;
    float* o = out + (size_t)b * OUT_BSTRIDE + n * 3;
    o[0] = px; o[1] = py; o[2] = pz;
}

// ---------------------------------------------------------------------------
// K1: radius-graph. 256 blocks x 512 thr; thread = (seg 0..15, pair 0..31)
// owning nodes {pair, pair+32} of the 64-node tile. Each pos[j] read feeds
// both nodes. Neighbor list: seg-major ascending == j-ascending (bit-exact).
// ---------------------------------------------------------------------------
__global__ __launch_bounds__(512, 2) void k_adj(const float* __restrict__ states,
                                                float* __restrict__ xs0,
                                                float* __restrict__ dinv,
                                                int* __restrict__ nbr,
                                                int* __restrict__ cntN) {
    const float R2c = 0.01f;
    int b = blockIdx.x & 7;
    int tile = blockIdx.x >> 3;     // 0..31 (64 nodes each)
    __shared__ float4 pos[NN];                       // 32 KiB
    __shared__ int degs[NSEG][64];                   // 4 KiB
    __shared__ unsigned short jb[512][2][SEGCAP];    // 12 KiB
    const float* sb = states + (size_t)b * NN * 6;
    for (int j = threadIdx.x; j < NN; j += 512) {
        const float* r = sb + j * 6;
        pos[j] = make_float4(r[0], r[1], r[2], 0.f);
    }
    __syncthreads();
    int pair = threadIdx.x & 31;     // node-pair id 0..31
    int seg  = threadIdx.x >> 5;     // 0..15
    int n0 = pair, n1 = pair + 32;   // local node ids
    int i0 = tile * 64 + n0;
    int i1 = tile * 64 + n1;
    int gi0 = b * NN + i0;
    int gi1 = b * NN + i1;
    float4 p0 = pos[i0];
    float4 p1 = pos[i1];
    int c0 = 0, c1 = 0;
    int j0 = seg * SEGJ;
#pragma unroll 4
    for (int j = j0; j < j0 + SEGJ; ++j) {
        float4 pj = pos[j];
        // exact np order: (dx*dx + dy*dy) + dz*dz, each op rounded, no fma
        float dx0 = p0.x - pj.x;
        float dy0 = p0.y - pj.y;
        float dz0 = p0.z - pj.z;
        float d2a = __fadd_rn(__fadd_rn(__fmul_rn(dx0, dx0), __fmul_rn(dy0, dy0)),
                              __fmul_rn(dz0, dz0));
        float dx1 = p1.x - pj.x;
        float dy1 = p1.y - pj.y;
        float dz1 = p1.z - pj.z;
        float d2b = __fadd_rn(__fadd_rn(__fmul_rn(dx1, dx1), __fmul_rn(dy1, dy1)),
                              __fmul_rn(dz1, dz1));
        if (d2a < R2c && j != i0) {
            if (c0 < SEGCAP) jb[threadIdx.x][0][c0] = (unsigned short)j;
            c0++;
        }
        if (d2b < R2c && j != i1) {
            if (c1 < SEGCAP) jb[threadIdx.x][1][c1] = (unsigned short)j;
            c1++;
        }
    }
    if (c0 > SEGCAP) c0 = SEGCAP;
    if (c1 > SEGCAP) c1 = SEGCAP;
    degs[seg][n0] = c0;
    degs[seg][n1] = c1;
    __syncthreads();
    int off0 = 0, off1 = 0;
    for (int s = 0; s < seg; ++s) {
        off0 += degs[s][n0];
        off1 += degs[s][n1];
    }
    int base0 = gi0 * MAXNBR + off0;
    for (int k = 0; k < c0; ++k) nbr[base0 + k] = (int)jb[threadIdx.x][0][k];
    int base1 = gi1 * MAXNBR + off1;
    for (int k = 0; k < c1; ++k) nbr[base1 + k] = (int)jb[threadIdx.x][1][k];
    if (seg == NSEG - 1) {
        int tot0 = off0 + c0;
        cntN[gi0] = tot0;
        float di0 = (float)(1.0 / sqrt((double)(1 + tot0)));  // exact rsqrt
        dinv[gi0] = di0;
        const float* srow0 = sb + (size_t)i0 * 6;
        float* xr0 = xs0 + (size_t)gi0 * 6;
#pragma unroll
        for (int c = 0; c < 6; ++c) xr0[c] = di0 * srow0[c];
        int tot1 = off1 + c1;
        cntN[gi1] = tot1;
        float di1 = (float)(1.0 / sqrt((double)(1 + tot1)));
        dinv[gi1] = di1;
        const float* srow1 = sb + (size_t)i1 * 6;
        float* xr1 = xs0 + (size_t)gi1 * 6;
#pragma unroll
        for (int c = 0; c < 6; ++c) xr1[c] = di1 * srow1[c];
    }
}

// ---------------------------------------------------------------------------
// K2: layer 0 (6 -> 128). 512 blocks x 512 thr: 32 nodes x 16 parts (8 ch).
// R15 chunk-4 gather (conditional loads, k-ascending adds). Verbatim.
// ---------------------------------------------------------------------------
__global__ __launch_bounds__(512, 4) void k_l0(const float* __restrict__ xs0,
                                               const float* __restrict__ dinv,
                                               const int* __restrict__ nbr,
                                               const int* __restrict__ cntN,
                                               const float* __restrict__ W0,
                                               const float* __restrict__ b0,
                                               float* __restrict__ xs1) {
    int b = blockIdx.x & 7;
    int tile = blockIdx.x >> 3;
    int node = threadIdx.x >> 4;   // 0..31
    int part = threadIdx.x & 15;   // 8 ch each
    int i = tile * 32 + node;
    int gi = b * NN + i;
    float g[6];
    {
        const float* sr = xs0 + (size_t)gi * 6;
        float2 a0 = *(const float2*)sr;
        float2 a1 = *(const float2*)(sr + 2);
        float2 a2 = *(const float2*)(sr + 4);
        g[0] = a0.x; g[1] = a0.y; g[2] = a1.x; g[3] = a1.y; g[4] = a2.x; g[5] = a2.y;
    }
    int cnt = cntN[gi];
    const int* nb = nbr + gi * MAXNBR;
    const float* xb = xs0 + (size_t)b * NN * 6;
    int k = 0;
    for (; k + 4 <= cnt; k += 4) {
        const float* r0 = xb + (size_t)nb[k]     * 6;
        const float* r1 = xb + (size_t)nb[k + 1] * 6;
        const float* r2 = xb + (size_t)nb[k + 2] * 6;
        const float* r3 = xb + (size_t)nb[k + 3] * 6;
        float2 v00 = *(const float2*)r0, v01 = *(const float2*)(r0 + 2), v02 = *(const float2*)(r0 + 4);
        float2 v10 = *(const float2*)r1, v11 = *(const float2*)(r1 + 2), v12 = *(const float2*)(r1 + 4);
        float2 v20 = *(const float2*)r2, v21 = *(const float2*)(r2 + 2), v22 = *(const float2*)(r2 + 4);
        float2 v30 = *(const float2*)r3, v31 = *(const float2*)(r3 + 2), v32 = *(const float2*)(r3 + 4);
        g[0] += v00.x; g[1] += v00.y; g[2] += v01.x; g[3] += v01.y; g[4] += v02.x; g[5] += v02.y;
        g[0] += v10.x; g[1] += v10.y; g[2] += v11.x; g[3] += v11.y; g[4] += v12.x; g[5] += v12.y;
        g[0] += v20.x; g[1] += v20.y; g[2] += v21.x; g[3] += v21.y; g[4] += v22.x; g[5] += v22.y;
        g[0] += v30.x; g[1] += v30.y; g[2] += v31.x; g[3] += v31.y; g[4] += v32.x; g[5] += v32.y;
    }
    for (; k < cnt; ++k) {
        int j = nb[k];
        const float* xr = xb + (size_t)j * 6;
        float2 v0 = *(const float2*)xr;
        float2 v1 = *(const float2*)(xr + 2);
        float2 v2 = *(const float2*)(xr + 4);
        g[0] += v0.x; g[1] += v0.y; g[2] += v1.x;
        g[3] += v1.y; g[4] += v2.x; g[5] += v2.y;
    }
    float di = dinv[gi];
#pragma unroll
    for (int c = 0; c < 6; ++c) g[c] *= di;
    int c0 = part * 8;
    float y[8];
#pragma unroll
    for (int r = 0; r < 2; ++r) {
        float4 bv = *(const float4*)(b0 + c0 + r * 4);
        y[r * 4 + 0] = bv.x; y[r * 4 + 1] = bv.y; y[r * 4 + 2] = bv.z; y[r * 4 + 3] = bv.w;
    }
#pragma unroll
    for (int kk = 0; kk < 6; ++kk) {
        float u = g[kk];
        const float* wr = W0 + kk * HH + c0;
#pragma unroll
        for (int r = 0; r < 2; ++r) {
            float4 w = *(const float4*)(wr + r * 4);
            y[r * 4 + 0] = fmaf(u, w.x, y[r * 4 + 0]);
            y[r * 4 + 1] = fmaf(u, w.y, y[r * 4 + 1]);
            y[r * 4 + 2] = fmaf(u, w.z, y[r * 4 + 2]);
            y[r * 4 + 3] = fmaf(u, w.w, y[r * 4 + 3]);
        }
    }
    float* xo = xs1 + (size_t)gi * HH + c0;
#pragma unroll
    for (int r = 0; r < 2; ++r) {
        float4 v;
        v.x = di * fmaxf(y[r * 4 + 0], 0.f);
        v.y = di * fmaxf(y[r * 4 + 1], 0.f);
        v.z = di * fmaxf(y[r * 4 + 2], 0.f);
        v.w = di * fmaxf(y[r * 4 + 3], 0.f);
        *(float4*)(xo + r * 4) = v;
    }
}

// ---------------------------------------------------------------------------
// 128->128 layers: 512 blocks x 512 thr, 32-node tiles, 16 waves/CU.
// Gather (R15 chunk-4, all 512 threads) -> uS. GEMM: 256 threads, each owns
// 4 nodes x 4 cols; per 32-row panel r-step: 4 uS b128 (2 uniq addr/wave)
// + 4 W b128 (512B uniq) + 64 fma. W LDS panels double-buffered.
// ---------------------------------------------------------------------------
__device__ __forceinline__ void gather_into_lds(const float* __restrict__ xin,
                                                const float* __restrict__ dinv,
                                                const int* __restrict__ nbr,
                                                const int* __restrict__ cntN,
                                                int b, int tile,
                                                float (*uS)[HH + 4]) {
    const int node = threadIdx.x >> 4;   // 0..31
    const int part = threadIdx.x & 15;   // 8 ch each
    const int i = tile * 32 + node;
    const int gi = b * NN + i;
    const int c0 = part * 8;
    float acc[8];
    const float* xs = xin + (size_t)gi * HH + c0;
#pragma unroll
    for (int r = 0; r < 2; ++r) *(float4*)&acc[r * 4] = *(const float4*)(xs + r * 4);
    const int cnt = cntN[gi];
    const int* nb = nbr + gi * MAXNBR;
    const float* xb = xin + (size_t)b * NN * HH + c0;
    int k = 0;
    for (; k + 4 <= cnt; k += 4) {
        const float* r0 = xb + (size_t)nb[k]     * HH;
        const float* r1 = xb + (size_t)nb[k + 1] * HH;
        const float* r2 = xb + (size_t)nb[k + 2] * HH;
        const float* r3 = xb + (size_t)nb[k + 3] * HH;
        float4 a0 = *(const float4*)r0, b0 = *(const float4*)(r0 + 4);
        float4 a1 = *(const float4*)r1, b1 = *(const float4*)(r1 + 4);
        float4 a2 = *(const float4*)r2, b2 = *(const float4*)(r2 + 4);
        float4 a3 = *(const float4*)r3, b3 = *(const float4*)(r3 + 4);
        acc[0] += a0.x; acc[1] += a0.y; acc[2] += a0.z; acc[3] += a0.w;
        acc[4] += b0.x; acc[5] += b0.y; acc[6] += b0.z; acc[7] += b0.w;
        acc[0] += a1.x; acc[1] += a1.y; acc[2] += a1.z; acc[3] += a1.w;
        acc[4] += b1.x; acc[5] += b1.y; acc[6] += b1.z; acc[7] += b1.w;
        acc[0] += a2.x; acc[1] += a2.y; acc[2] += a2.z; acc[3] += a2.w;
        acc[4] += b2.x; acc[5] += b2.y; acc[6] += b2.z; acc[7] += b2.w;
        acc[0] += a3.x; acc[1] += a3.y; acc[2] += a3.z; acc[3] += a3.w;
        acc[4] += b3.x; acc[5] += b3.y; acc[6] += b3.z; acc[7] += b3.w;
    }
    for (; k < cnt; ++k) {
        const int j = nb[k];
        const float* xr = xb + (size_t)j * HH;
#pragma unroll
        for (int r = 0; r < 2; ++r) {
            float v[4];
            *(float4*)v = *(const float4*)(xr + r * 4);
            acc[r * 4 + 0] += v[0]; acc[r * 4 + 1] += v[1];
            acc[r * 4 + 2] += v[2]; acc[r * 4 + 3] += v[3];
        }
    }
    const float di = dinv[gi];
#pragma unroll
    for (int r = 0; r < 2; ++r) {
        float4 o;
        o.x = acc[r * 4 + 0] * di; o.y = acc[r * 4 + 1] * di;
        o.z = acc[r * 4 + 2] * di; o.w = acc[r * 4 + 3] * di;
        *(float4*)&uS[node][c0 + r * 4] = o;
    }
}

// GEMM over one 32-row W panel in LDS. Thread owns 4 nodes x 4 channels;
// one W float4 feeds all 4 nodes, one uS b128 covers 4 k's of one node.
// Per-output k-ascending fmaf order -> bit-identical to 2n4c / 1n8c.
__device__ __forceinline__ void gemm_panel4(const float (*uS)[HH + 4],
                                            const float* __restrict__ wbuf,
                                            int p, int nbase, int cA,
                                            float y[16]) {
#pragma unroll
    for (int r = 0; r < 32; r += 4) {
        float ua[16];
        *(float4*)&ua[0]  = *(const float4*)(&uS[nbase + 0][p * 32 + r]);
        *(float4*)&ua[4]  = *(const float4*)(&uS[nbase + 1][p * 32 + r]);
        *(float4*)&ua[8]  = *(const float4*)(&uS[nbase + 2][p * 32 + r]);
        *(float4*)&ua[12] = *(const float4*)(&uS[nbase + 3][p * 32 + r]);
        const float* wrow = wbuf + r * HH + cA;
#pragma unroll
        for (int q = 0; q < 4; ++q) {
            float4 w = *(const float4*)(wrow + q * HH);
#pragma unroll
            for (int n = 0; n < 4; ++n) {
                float uq = ua[n * 4 + q];
                y[n * 4 + 0] = fmaf(uq, w.x, y[n * 4 + 0]);
                y[n * 4 + 1] = fmaf(uq, w.y, y[n * 4 + 1]);
                y[n * 4 + 2] = fmaf(uq, w.z, y[n * 4 + 2]);
                y[n * 4 + 3] = fmaf(uq, w.w, y[n * 4 + 3]);
            }
        }
    }
}

// K3: middle layer (layer 1): xs_out = dinv * relu(u @ W + b)
__global__ __launch_bounds__(512, 4) void k_mid(const float* __restrict__ xin,
                                                const float* __restrict__ dinv,
                                                const int* __restrict__ nbr,
                                                const int* __restrict__ cntN,
                                                const float* __restrict__ W,
                                                const float* __restrict__ bias,
                                                float* __restrict__ xout) {
    __shared__ __align__(16) float uS[32][HH + 4];   // 16.9 KB
    __shared__ __align__(16) float wS[2][32 * HH];   // 32 KB
    int b = blockIdx.x & 7;
    int tile = blockIdx.x >> 3;
    int t = threadIdx.x;
    const float4* Wf4 = (const float4*)W;
    float4 wreg[2];
    wreg[0] = Wf4[t]; wreg[1] = Wf4[t + 512];   // panel 0
    gather_into_lds(xin, dinv, nbr, cntN, b, tile, uS);
    {
        float4* ws4 = (float4*)wS[0];
        ws4[t] = wreg[0]; ws4[t + 512] = wreg[1];
    }
    __syncthreads();
    const int cq = t & 31, nq = t >> 5;   // nq 0..15; GEMM active for nq<8
    const int cA = cq * 4;
    const int nbase = (nq & 7) * 4;
    const bool act = (nq < 8);
    float y[16];
    if (act) {
        float4 bv = *(const float4*)(bias + cA);
#pragma unroll
        for (int n = 0; n < 4; ++n) {
            y[n * 4 + 0] = bv.x; y[n * 4 + 1] = bv.y;
            y[n * 4 + 2] = bv.z; y[n * 4 + 3] = bv.w;
        }
    }
#pragma unroll
    for (int p = 0; p < 4; ++p) {
        if (p < 3) {
            wreg[0] = Wf4[(p + 1) * 1024 + t];
            wreg[1] = Wf4[(p + 1) * 1024 + t + 512];
        }
        if (act) gemm_panel4(uS, wS[p & 1], p, nbase, cA, y);
        if (p < 3) {
            float4* ws4 = (float4*)wS[1 - (p & 1)];
            ws4[t] = wreg[0]; ws4[t + 512] = wreg[1];
            __syncthreads();
        }
    }
    if (act) {
        const int gbase = b * NN + tile * 32 + nbase;
#pragma unroll
        for (int n = 0; n < 4; ++n) {
            float dv = dinv[gbase + n];
            float4 o;
            o.x = dv * fmaxf(y[n * 4 + 0], 0.f);
            o.y = dv * fmaxf(y[n * 4 + 1], 0.f);
            o.z = dv * fmaxf(y[n * 4 + 2], 0.f);
            o.w = dv * fmaxf(y[n * 4 + 3], 0.f);
            *(float4*)(xout + (size_t)(gbase + n) * HH + cA) = o;
        }
    }
}

// K4: layer 2 + FC head + state update + output write.
// After the last panel, wS[0] is reused as y3[32][128] and wS[1] as wfcS.
__global__ __launch_bounds__(512, 4) void k_last(const float* __restrict__ xin,
                                                 const float* __restrict__ dinv,
                                                 const int* __restrict__ nbr,
                                                 const int* __restrict__ cntN,
                                                 const float* __restrict__ W2,
                                                 const float* __restrict__ b2,
                                                 const float* __restrict__ Wfc,
                                                 const float* __restrict__ bfc,
                                                 const float* __restrict__ padding,
                                                 float* __restrict__ states,
                                                 float* __restrict__ outt) {
    __shared__ __align__(16) float uS[32][HH + 4];   // 16.9 KB
    __shared__ __align__(16) float wS[2][32 * HH];   // 32 KB
    int b = blockIdx.x & 7;
    int tile = blockIdx.x >> 3;
    int t = threadIdx.x;
    const float4* Wf4 = (const float4*)W2;
    float4 wreg[2];
    wreg[0] = Wf4[t]; wreg[1] = Wf4[t + 512];
    gather_into_lds(xin, dinv, nbr, cntN, b, tile, uS);
    {
        float4* ws4 = (float4*)wS[0];
        ws4[t] = wreg[0]; ws4[t + 512] = wreg[1];
    }
    __syncthreads();
    const int cq = t & 31, nq = t >> 5;
    const int cA = cq * 4;
    const int nbase = (nq & 7) * 4;
    const bool act = (nq < 8);
    float y[16];
    if (act) {
        float4 bv = *(const float4*)(b2 + cA);
#pragma unroll
        for (int n = 0; n < 4; ++n) {
            y[n * 4 + 0] = bv.x; y[n * 4 + 1] = bv.y;
            y[n * 4 + 2] = bv.z; y[n * 4 + 3] = bv.w;
        }
    }
#pragma unroll
    for (int p = 0; p < 4; ++p) {
        if (p < 3) {
            wreg[0] = Wf4[(p + 1) * 1024 + t];
            wreg[1] = Wf4[(p + 1) * 1024 + t + 512];
        }
        if (act) gemm_panel4(uS, wS[p & 1], p, nbase, cA, y);
        if (p < 3) {
            float4* ws4 = (float4*)wS[1 - (p & 1)];
            ws4[t] = wreg[0]; ws4[t + 512] = wreg[1];
            __syncthreads();
        }
    }
    __syncthreads();   // all panel reads done; reuse wS
    float* y3  = wS[0];   // [32][HH]
    float* wfc = wS[1];   // HH*6 floats
    for (int q = t; q < HH * 6; q += 512) wfc[q] = Wfc[q];
    if (act) {
#pragma unroll
        for (int n = 0; n < 4; ++n) {
            float4 v;
            v.x = fmaxf(y[n * 4 + 0], 0.f);
            v.y = fmaxf(y[n * 4 + 1], 0.f);
            v.z = fmaxf(y[n * 4 + 2], 0.f);
            v.w = fmaxf(y[n * 4 + 3], 0.f);
            *(float4*)&y3[(nbase + n) * HH + cA] = v;
        }
    }
    __syncthreads();
    if (t < 192) {
        int n = t / 6;
        int c = t - n * 6;
        float r = bfc[c];
        for (int k = 0; k < HH; k += 4) {
            float yv[4];
            *(float4*)yv = *(const float4*)&y3[n * HH + k];
            r = fmaf(yv[0], wfc[(k + 0) * 6 + c], r);
            r = fmaf(yv[1], wfc[(k + 1) * 6 + c], r);
            r = fmaf(yv[2], wfc[(k + 2) * 6 + c], r);
            r = fmaf(yv[3], wfc[(k + 3) * 6 + c], r);
        }
        int i = tile * 32 + n;
        int gi = b * NN + i;
        float pv = padding[b * NN + i];   // all-ones in this setup
        float s = states[(size_t)gi * 6 + c] + r * pv;
        states[(size_t)gi * 6 + c] = s;
        if (c < 3) outt[(size_t)b * OUT_BSTRIDE + i * 3 + c] = s;
    }
}

// ---------------------------------------------------------------------------
extern "C" void kernel_launch(void* const* d_in, const int* in_sizes, int n_in,
                              void* d_out, int out_size, void* d_ws, size_t ws_size,
                              hipStream_t stream) {
    (void)in_sizes; (void)n_in; (void)out_size; (void)ws_size;
    const float* points  = (const float*)d_in[0];
    const float* padding = (const float*)d_in[5];
    const float* W0  = (const float*)d_in[6];
    const float* b0  = (const float*)d_in[7];
    const float* W1  = (const float*)d_in[8];
    const float* b1  = (const float*)d_in[9];
    const float* W2  = (const float*)d_in[10];
    const float* b2  = (const float*)d_in[11];
    const float* Wfc = (const float*)d_in[12];
    const float* bfc = (const float*)d_in[13];
    float* out = (float*)d_out;

    // workspace carve-up (~24 MB)
    float* ws     = (float*)d_ws;
    float* states = ws;                       // BB*NN*6
    float* xs0    = states + BB * NN * 6;     // BB*NN*6
    float* xs1    = xs0 + BB * NN * 6;        // BB*NN*HH
    float* xs2    = xs1 + BB * NN * HH;       // BB*NN*HH
    float* dinvp  = xs2 + BB * NN * HH;       // BB*NN
    int*   nbr    = (int*)(dinvp + BB * NN);  // BB*NN*MAXNBR
    int*   cntN   = nbr + BB * NN * MAXNBR;   // BB*NN

    k_init<<<(BB * NN) / 256, 256, 0, stream>>>(points, states, out);
    for (int t = 0; t < PREDL; ++t) {
        k_adj<<<256, 512, 0, stream>>>(states, xs0, dinvp, nbr, cntN);
        k_l0<<<512, 512, 0, stream>>>(xs0, dinvp, nbr, cntN, W0, b0, xs1);
        k_mid<<<512, 512, 0, stream>>>(xs1, dinvp, nbr, cntN, W1, b1, xs2);
        k_last<<<512, 512, 0, stream>>>(xs2, dinvp, nbr, cntN, W2, b2, Wfc, bfc,
                                        padding, states,
                                        out + (size_t)(t + 1) * TSTRIDE);
    }
}

// Round 6
// 655.264 us; speedup vs baseline: 1.1863x; 1.0021x over previous
//
#include <hip/hip_runtime.h>
#include <math.h>

// Problem constants (fixed by setup_inputs)
#define BB 8
#define NN 2048
#define HH 128
#define NSEG 16            // j-segments per node (128 j's each)
#define SEGJ 128
#define SEGCAP 12          // R20: back to 12 (R19's 6 truncated: absmax 0.171875)
#define MAXNBR 96          // slab ints per node (empirical max degree << 96)
#define PREDL 10
#define TSTRIDE (NN*3)
#define OUT_BSTRIDE ((PREDL+1)*NN*3)

// R20 = R19 (k_adj pair-partition, -34 us verified) + SEGCAP 6->12.
// R19 lesson: 6@128j truncated a few neighbor lists (absmax 0.03125 ->
// 0.171875). 12@128j is strictly safer than the verified-exact 12@256j
// (any 128-window count <= containing 256-window count) -> zero truncation,
// bit-identical. jb LDS 12->24 KB; k_adj total 60 KB, still 2 blocks/CU.
// Falsified so far: speculative gather (R16 +2.5%), readlane GEMM (R17
// +12%), GEMM LDS cuts beyond R18 (neutral), SEGCAP=6 (R19 inexact),
// grid-sync/fusion/occupancy changes (previous session R4/R5/R8/R9/R13).

// ---------------------------------------------------------------------------
// K0: states0 = [points, 0]; write t=0 output slice
// ---------------------------------------------------------------------------
__global__ __launch_bounds__(256) void k_init(const float* __restrict__ points,
                                              float* __restrict__ states,
                                              float* __restrict__ out) {
    int idx = blockIdx.x * 256 + threadIdx.x;
    if (idx >= BB * NN) return;
    int b = idx >> 11;
    int n = idx & 2047;
    float px = points[idx * 3 + 0];
    float py = points[idx * 3 + 1];
    float pz = points[idx * 3 + 2];
    float* s = states + (size_t)idx * 6;
    s[0] = px; s[1] = py; s[2] = pz; s[3] = 0.f; s[4] = 0.f; s[5] = 0.f;
    float* o = out + (size_t)b * OUT_BSTRIDE + n * 3;
    o[0] = px; o[1] = py; o[2] = pz;
}

// ---------------------------------------------------------------------------
// K1: radius-graph. 256 blocks x 512 thr; thread = (seg 0..15, pair 0..31)
// owning nodes {pair, pair+32} of the 64-node tile. Each pos[j] read feeds
// both nodes. Neighbor list: seg-major ascending == j-ascending (bit-exact).
// ---------------------------------------------------------------------------
__global__ __launch_bounds__(512, 2) void k_adj(const float* __restrict__ states,
                                                float* __restrict__ xs0,
                                                float* __restrict__ dinv,
                                                int* __restrict__ nbr,
                                                int* __restrict__ cntN) {
    const float R2c = 0.01f;
    int b = blockIdx.x & 7;
    int tile = blockIdx.x >> 3;     // 0..31 (64 nodes each)
    __shared__ float4 pos[NN];                       // 32 KiB
    __shared__ int degs[NSEG][64];                   // 4 KiB
    __shared__ unsigned short jb[512][2][SEGCAP];    // 24 KiB
    const float* sb = states + (size_t)b * NN * 6;
    for (int j = threadIdx.x; j < NN; j += 512) {
        const float* r = sb + j * 6;
        pos[j] = make_float4(r[0], r[1], r[2], 0.f);
    }
    __syncthreads();
    int pair = threadIdx.x & 31;     // node-pair id 0..31
    int seg  = threadIdx.x >> 5;     // 0..15
    int n0 = pair, n1 = pair + 32;   // local node ids
    int i0 = tile * 64 + n0;
    int i1 = tile * 64 + n1;
    int gi0 = b * NN + i0;
    int gi1 = b * NN + i1;
    float4 p0 = pos[i0];
    float4 p1 = pos[i1];
    int c0 = 0, c1 = 0;
    int j0 = seg * SEGJ;
#pragma unroll 4
    for (int j = j0; j < j0 + SEGJ; ++j) {
        float4 pj = pos[j];
        // exact np order: (dx*dx + dy*dy) + dz*dz, each op rounded, no fma
        float dx0 = p0.x - pj.x;
        float dy0 = p0.y - pj.y;
        float dz0 = p0.z - pj.z;
        float d2a = __fadd_rn(__fadd_rn(__fmul_rn(dx0, dx0), __fmul_rn(dy0, dy0)),
                              __fmul_rn(dz0, dz0));
        float dx1 = p1.x - pj.x;
        float dy1 = p1.y - pj.y;
        float dz1 = p1.z - pj.z;
        float d2b = __fadd_rn(__fadd_rn(__fmul_rn(dx1, dx1), __fmul_rn(dy1, dy1)),
                              __fmul_rn(dz1, dz1));
        if (d2a < R2c && j != i0) {
            if (c0 < SEGCAP) jb[threadIdx.x][0][c0] = (unsigned short)j;
            c0++;
        }
        if (d2b < R2c && j != i1) {
            if (c1 < SEGCAP) jb[threadIdx.x][1][c1] = (unsigned short)j;
            c1++;
        }
    }
    if (c0 > SEGCAP) c0 = SEGCAP;
    if (c1 > SEGCAP) c1 = SEGCAP;
    degs[seg][n0] = c0;
    degs[seg][n1] = c1;
    __syncthreads();
    int off0 = 0, off1 = 0;
    for (int s = 0; s < seg; ++s) {
        off0 += degs[s][n0];
        off1 += degs[s][n1];
    }
    int base0 = gi0 * MAXNBR + off0;
    for (int k = 0; k < c0; ++k) nbr[base0 + k] = (int)jb[threadIdx.x][0][k];
    int base1 = gi1 * MAXNBR + off1;
    for (int k = 0; k < c1; ++k) nbr[base1 + k] = (int)jb[threadIdx.x][1][k];
    if (seg == NSEG - 1) {
        int tot0 = off0 + c0;
        cntN[gi0] = tot0;
        float di0 = (float)(1.0 / sqrt((double)(1 + tot0)));  // exact rsqrt
        dinv[gi0] = di0;
        const float* srow0 = sb + (size_t)i0 * 6;
        float* xr0 = xs0 + (size_t)gi0 * 6;
#pragma unroll
        for (int c = 0; c < 6; ++c) xr0[c] = di0 * srow0[c];
        int tot1 = off1 + c1;
        cntN[gi1] = tot1;
        float di1 = (float)(1.0 / sqrt((double)(1 + tot1)));
        dinv[gi1] = di1;
        const float* srow1 = sb + (size_t)i1 * 6;
        float* xr1 = xs0 + (size_t)gi1 * 6;
#pragma unroll
        for (int c = 0; c < 6; ++c) xr1[c] = di1 * srow1[c];
    }
}

// ---------------------------------------------------------------------------
// K2: layer 0 (6 -> 128). 512 blocks x 512 thr: 32 nodes x 16 parts (8 ch).
// R15 chunk-4 gather (conditional loads, k-ascending adds). Verbatim.
// ---------------------------------------------------------------------------
__global__ __launch_bounds__(512, 4) void k_l0(const float* __restrict__ xs0,
                                               const float* __restrict__ dinv,
                                               const int* __restrict__ nbr,
                                               const int* __restrict__ cntN,
                                               const float* __restrict__ W0,
                                               const float* __restrict__ b0,
                                               float* __restrict__ xs1) {
    int b = blockIdx.x & 7;
    int tile = blockIdx.x >> 3;
    int node = threadIdx.x >> 4;   // 0..31
    int part = threadIdx.x & 15;   // 8 ch each
    int i = tile * 32 + node;
    int gi = b * NN + i;
    float g[6];
    {
        const float* sr = xs0 + (size_t)gi * 6;
        float2 a0 = *(const float2*)sr;
        float2 a1 = *(const float2*)(sr + 2);
        float2 a2 = *(const float2*)(sr + 4);
        g[0] = a0.x; g[1] = a0.y; g[2] = a1.x; g[3] = a1.y; g[4] = a2.x; g[5] = a2.y;
    }
    int cnt = cntN[gi];
    const int* nb = nbr + gi * MAXNBR;
    const float* xb = xs0 + (size_t)b * NN * 6;
    int k = 0;
    for (; k + 4 <= cnt; k += 4) {
        const float* r0 = xb + (size_t)nb[k]     * 6;
        const float* r1 = xb + (size_t)nb[k + 1] * 6;
        const float* r2 = xb + (size_t)nb[k + 2] * 6;
        const float* r3 = xb + (size_t)nb[k + 3] * 6;
        float2 v00 = *(const float2*)r0, v01 = *(const float2*)(r0 + 2), v02 = *(const float2*)(r0 + 4);
        float2 v10 = *(const float2*)r1, v11 = *(const float2*)(r1 + 2), v12 = *(const float2*)(r1 + 4);
        float2 v20 = *(const float2*)r2, v21 = *(const float2*)(r2 + 2), v22 = *(const float2*)(r2 + 4);
        float2 v30 = *(const float2*)r3, v31 = *(const float2*)(r3 + 2), v32 = *(const float2*)(r3 + 4);
        g[0] += v00.x; g[1] += v00.y; g[2] += v01.x; g[3] += v01.y; g[4] += v02.x; g[5] += v02.y;
        g[0] += v10.x; g[1] += v10.y; g[2] += v11.x; g[3] += v11.y; g[4] += v12.x; g[5] += v12.y;
        g[0] += v20.x; g[1] += v20.y; g[2] += v21.x; g[3] += v21.y; g[4] += v22.x; g[5] += v22.y;
        g[0] += v30.x; g[1] += v30.y; g[2] += v31.x; g[3] += v31.y; g[4] += v32.x; g[5] += v32.y;
    }
    for (; k < cnt; ++k) {
        int j = nb[k];
        const float* xr = xb + (size_t)j * 6;
        float2 v0 = *(const float2*)xr;
        float2 v1 = *(const float2*)(xr + 2);
        float2 v2 = *(const float2*)(xr + 4);
        g[0] += v0.x; g[1] += v0.y; g[2] += v1.x;
        g[3] += v1.y; g[4] += v2.x; g[5] += v2.y;
    }
    float di = dinv[gi];
#pragma unroll
    for (int c = 0; c < 6; ++c) g[c] *= di;
    int c0 = part * 8;
    float y[8];
#pragma unroll
    for (int r = 0; r < 2; ++r) {
        float4 bv = *(const float4*)(b0 + c0 + r * 4);
        y[r * 4 + 0] = bv.x; y[r * 4 + 1] = bv.y; y[r * 4 + 2] = bv.z; y[r * 4 + 3] = bv.w;
    }
#pragma unroll
    for (int kk = 0; kk < 6; ++kk) {
        float u = g[kk];
        const float* wr = W0 + kk * HH + c0;
#pragma unroll
        for (int r = 0; r < 2; ++r) {
            float4 w = *(const float4*)(wr + r * 4);
            y[r * 4 + 0] = fmaf(u, w.x, y[r * 4 + 0]);
            y[r * 4 + 1] = fmaf(u, w.y, y[r * 4 + 1]);
            y[r * 4 + 2] = fmaf(u, w.z, y[r * 4 + 2]);
            y[r * 4 + 3] = fmaf(u, w.w, y[r * 4 + 3]);
        }
    }
    float* xo = xs1 + (size_t)gi * HH + c0;
#pragma unroll
    for (int r = 0; r < 2; ++r) {
        float4 v;
        v.x = di * fmaxf(y[r * 4 + 0], 0.f);
        v.y = di * fmaxf(y[r * 4 + 1], 0.f);
        v.z = di * fmaxf(y[r * 4 + 2], 0.f);
        v.w = di * fmaxf(y[r * 4 + 3], 0.f);
        *(float4*)(xo + r * 4) = v;
    }
}

// ---------------------------------------------------------------------------
// 128->128 layers: 512 blocks x 512 thr, 32-node tiles, 16 waves/CU.
// Gather (R15 chunk-4, all 512 threads) -> uS. GEMM: 256 threads, each owns
// 4 nodes x 4 cols; per 32-row panel r-step: 4 uS b128 (2 uniq addr/wave)
// + 4 W b128 (512B uniq) + 64 fma. W LDS panels double-buffered.
// ---------------------------------------------------------------------------
__device__ __forceinline__ void gather_into_lds(const float* __restrict__ xin,
                                                const float* __restrict__ dinv,
                                                const int* __restrict__ nbr,
                                                const int* __restrict__ cntN,
                                                int b, int tile,
                                                float (*uS)[HH + 4]) {
    const int node = threadIdx.x >> 4;   // 0..31
    const int part = threadIdx.x & 15;   // 8 ch each
    const int i = tile * 32 + node;
    const int gi = b * NN + i;
    const int c0 = part * 8;
    float acc[8];
    const float* xs = xin + (size_t)gi * HH + c0;
#pragma unroll
    for (int r = 0; r < 2; ++r) *(float4*)&acc[r * 4] = *(const float4*)(xs + r * 4);
    const int cnt = cntN[gi];
    const int* nb = nbr + gi * MAXNBR;
    const float* xb = xin + (size_t)b * NN * HH + c0;
    int k = 0;
    for (; k + 4 <= cnt; k += 4) {
        const float* r0 = xb + (size_t)nb[k]     * HH;
        const float* r1 = xb + (size_t)nb[k + 1] * HH;
        const float* r2 = xb + (size_t)nb[k + 2] * HH;
        const float* r3 = xb + (size_t)nb[k + 3] * HH;
        float4 a0 = *(const float4*)r0, b0 = *(const float4*)(r0 + 4);
        float4 a1 = *(const float4*)r1, b1 = *(const float4*)(r1 + 4);
        float4 a2 = *(const float4*)r2, b2 = *(const float4*)(r2 + 4);
        float4 a3 = *(const float4*)r3, b3 = *(const float4*)(r3 + 4);
        acc[0] += a0.x; acc[1] += a0.y; acc[2] += a0.z; acc[3] += a0.w;
        acc[4] += b0.x; acc[5] += b0.y; acc[6] += b0.z; acc[7] += b0.w;
        acc[0] += a1.x; acc[1] += a1.y; acc[2] += a1.z; acc[3] += a1.w;
        acc[4] += b1.x; acc[5] += b1.y; acc[6] += b1.z; acc[7] += b1.w;
        acc[0] += a2.x; acc[1] += a2.y; acc[2] += a2.z; acc[3] += a2.w;
        acc[4] += b2.x; acc[5] += b2.y; acc[6] += b2.z; acc[7] += b2.w;
        acc[0] += a3.x; acc[1] += a3.y; acc[2] += a3.z; acc[3] += a3.w;
        acc[4] += b3.x; acc[5] += b3.y; acc[6] += b3.z; acc[7] += b3.w;
    }
    for (; k < cnt; ++k) {
        const int j = nb[k];
        const float* xr = xb + (size_t)j * HH;
#pragma unroll
        for (int r = 0; r < 2; ++r) {
            float v[4];
            *(float4*)v = *(const float4*)(xr + r * 4);
            acc[r * 4 + 0] += v[0]; acc[r * 4 + 1] += v[1];
            acc[r * 4 + 2] += v[2]; acc[r * 4 + 3] += v[3];
        }
    }
    const float di = dinv[gi];
#pragma unroll
    for (int r = 0; r < 2; ++r) {
        float4 o;
        o.x = acc[r * 4 + 0] * di; o.y = acc[r * 4 + 1] * di;
        o.z = acc[r * 4 + 2] * di; o.w = acc[r * 4 + 3] * di;
        *(float4*)&uS[node][c0 + r * 4] = o;
    }
}

// GEMM over one 32-row W panel in LDS. Thread owns 4 nodes x 4 channels;
// one W float4 feeds all 4 nodes, one uS b128 covers 4 k's of one node.
// Per-output k-ascending fmaf order -> bit-identical to 2n4c / 1n8c.
__device__ __forceinline__ void gemm_panel4(const float (*uS)[HH + 4],
                                            const float* __restrict__ wbuf,
                                            int p, int nbase, int cA,
                                            float y[16]) {
#pragma unroll
    for (int r = 0; r < 32; r += 4) {
        float ua[16];
        *(float4*)&ua[0]  = *(const float4*)(&uS[nbase + 0][p * 32 + r]);
        *(float4*)&ua[4]  = *(const float4*)(&uS[nbase + 1][p * 32 + r]);
        *(float4*)&ua[8]  = *(const float4*)(&uS[nbase + 2][p * 32 + r]);
        *(float4*)&ua[12] = *(const float4*)(&uS[nbase + 3][p * 32 + r]);
        const float* wrow = wbuf + r * HH + cA;
#pragma unroll
        for (int q = 0; q < 4; ++q) {
            float4 w = *(const float4*)(wrow + q * HH);
#pragma unroll
            for (int n = 0; n < 4; ++n) {
                float uq = ua[n * 4 + q];
                y[n * 4 + 0] = fmaf(uq, w.x, y[n * 4 + 0]);
                y[n * 4 + 1] = fmaf(uq, w.y, y[n * 4 + 1]);
                y[n * 4 + 2] = fmaf(uq, w.z, y[n * 4 + 2]);
                y[n * 4 + 3] = fmaf(uq, w.w, y[n * 4 + 3]);
            }
        }
    }
}

// K3: middle layer (layer 1): xs_out = dinv * relu(u @ W + b)
__global__ __launch_bounds__(512, 4) void k_mid(const float* __restrict__ xin,
                                                const float* __restrict__ dinv,
                                                const int* __restrict__ nbr,
                                                const int* __restrict__ cntN,
                                                const float* __restrict__ W,
                                                const float* __restrict__ bias,
                                                float* __restrict__ xout) {
    __shared__ __align__(16) float uS[32][HH + 4];   // 16.9 KB
    __shared__ __align__(16) float wS[2][32 * HH];   // 32 KB
    int b = blockIdx.x & 7;
    int tile = blockIdx.x >> 3;
    int t = threadIdx.x;
    const float4* Wf4 = (const float4*)W;
    float4 wreg[2];
    wreg[0] = Wf4[t]; wreg[1] = Wf4[t + 512];   // panel 0
    gather_into_lds(xin, dinv, nbr, cntN, b, tile, uS);
    {
        float4* ws4 = (float4*)wS[0];
        ws4[t] = wreg[0]; ws4[t + 512] = wreg[1];
    }
    __syncthreads();
    const int cq = t & 31, nq = t >> 5;   // nq 0..15; GEMM active for nq<8
    const int cA = cq * 4;
    const int nbase = (nq & 7) * 4;
    const bool act = (nq < 8);
    float y[16];
    if (act) {
        float4 bv = *(const float4*)(bias + cA);
#pragma unroll
        for (int n = 0; n < 4; ++n) {
            y[n * 4 + 0] = bv.x; y[n * 4 + 1] = bv.y;
            y[n * 4 + 2] = bv.z; y[n * 4 + 3] = bv.w;
        }
    }
#pragma unroll
    for (int p = 0; p < 4; ++p) {
        if (p < 3) {
            wreg[0] = Wf4[(p + 1) * 1024 + t];
            wreg[1] = Wf4[(p + 1) * 1024 + t + 512];
        }
        if (act) gemm_panel4(uS, wS[p & 1], p, nbase, cA, y);
        if (p < 3) {
            float4* ws4 = (float4*)wS[1 - (p & 1)];
            ws4[t] = wreg[0]; ws4[t + 512] = wreg[1];
            __syncthreads();
        }
    }
    if (act) {
        const int gbase = b * NN + tile * 32 + nbase;
#pragma unroll
        for (int n = 0; n < 4; ++n) {
            float dv = dinv[gbase + n];
            float4 o;
            o.x = dv * fmaxf(y[n * 4 + 0], 0.f);
            o.y = dv * fmaxf(y[n * 4 + 1], 0.f);
            o.z = dv * fmaxf(y[n * 4 + 2], 0.f);
            o.w = dv * fmaxf(y[n * 4 + 3], 0.f);
            *(float4*)(xout + (size_t)(gbase + n) * HH + cA) = o;
        }
    }
}

// K4: layer 2 + FC head + state update + output write.
// After the last panel, wS[0] is reused as y3[32][128] and wS[1] as wfcS.
__global__ __launch_bounds__(512, 4) void k_last(const float* __restrict__ xin,
                                                 const float* __restrict__ dinv,
                                                 const int* __restrict__ nbr,
                                                 const int* __restrict__ cntN,
                                                 const float* __restrict__ W2,
                                                 const float* __restrict__ b2,
                                                 const float* __restrict__ Wfc,
                                                 const float* __restrict__ bfc,
                                                 const float* __restrict__ padding,
                                                 float* __restrict__ states,
                                                 float* __restrict__ outt) {
    __shared__ __align__(16) float uS[32][HH + 4];   // 16.9 KB
    __shared__ __align__(16) float wS[2][32 * HH];   // 32 KB
    int b = blockIdx.x & 7;
    int tile = blockIdx.x >> 3;
    int t = threadIdx.x;
    const float4* Wf4 = (const float4*)W2;
    float4 wreg[2];
    wreg[0] = Wf4[t]; wreg[1] = Wf4[t + 512];
    gather_into_lds(xin, dinv, nbr, cntN, b, tile, uS);
    {
        float4* ws4 = (float4*)wS[0];
        ws4[t] = wreg[0]; ws4[t + 512] = wreg[1];
    }
    __syncthreads();
    const int cq = t & 31, nq = t >> 5;
    const int cA = cq * 4;
    const int nbase = (nq & 7) * 4;
    const bool act = (nq < 8);
    float y[16];
    if (act) {
        float4 bv = *(const float4*)(b2 + cA);
#pragma unroll
        for (int n = 0; n < 4; ++n) {
            y[n * 4 + 0] = bv.x; y[n * 4 + 1] = bv.y;
            y[n * 4 + 2] = bv.z; y[n * 4 + 3] = bv.w;
        }
    }
#pragma unroll
    for (int p = 0; p < 4; ++p) {
        if (p < 3) {
            wreg[0] = Wf4[(p + 1) * 1024 + t];
            wreg[1] = Wf4[(p + 1) * 1024 + t + 512];
        }
        if (act) gemm_panel4(uS, wS[p & 1], p, nbase, cA, y);
        if (p < 3) {
            float4* ws4 = (float4*)wS[1 - (p & 1)];
            ws4[t] = wreg[0]; ws4[t + 512] = wreg[1];
            __syncthreads();
        }
    }
    __syncthreads();   // all panel reads done; reuse wS
    float* y3  = wS[0];   // [32][HH]
    float* wfc = wS[1];   // HH*6 floats
    for (int q = t; q < HH * 6; q += 512) wfc[q] = Wfc[q];
    if (act) {
#pragma unroll
        for (int n = 0; n < 4; ++n) {
            float4 v;
            v.x = fmaxf(y[n * 4 + 0], 0.f);
            v.y = fmaxf(y[n * 4 + 1], 0.f);
            v.z = fmaxf(y[n * 4 + 2], 0.f);
            v.w = fmaxf(y[n * 4 + 3], 0.f);
            *(float4*)&y3[(nbase + n) * HH + cA] = v;
        }
    }
    __syncthreads();
    if (t < 192) {
        int n = t / 6;
        int c = t - n * 6;
        float r = bfc[c];
        for (int k = 0; k < HH; k += 4) {
            float yv[4];
            *(float4*)yv = *(const float4*)&y3[n * HH + k];
            r = fmaf(yv[0], wfc[(k + 0) * 6 + c], r);
            r = fmaf(yv[1], wfc[(k + 1) * 6 + c], r);
            r = fmaf(yv[2], wfc[(k + 2) * 6 + c], r);
            r = fmaf(yv[3], wfc[(k + 3) * 6 + c], r);
        }
        int i = tile * 32 + n;
        int gi = b * NN + i;
        float pv = padding[b * NN + i];   // all-ones in this setup
        float s = states[(size_t)gi * 6 + c] + r * pv;
        states[(size_t)gi * 6 + c] = s;
        if (c < 3) outt[(size_t)b * OUT_BSTRIDE + i * 3 + c] = s;
    }
}

// ---------------------------------------------------------------------------
extern "C" void kernel_launch(void* const* d_in, const int* in_sizes, int n_in,
                              void* d_out, int out_size, void* d_ws, size_t ws_size,
                              hipStream_t stream) {
    (void)in_sizes; (void)n_in; (void)out_size; (void)ws_size;
    const float* points  = (const float*)d_in[0];
    const float* padding = (const float*)d_in[5];
    const float* W0  = (const float*)d_in[6];
    const float* b0  = (const float*)d_in[7];
    const float* W1  = (const float*)d_in[8];
    const float* b1  = (const float*)d_in[9];
    const float* W2  = (const float*)d_in[10];
    const float* b2  = (const float*)d_in[11];
    const float* Wfc = (const float*)d_in[12];
    const float* bfc = (const float*)d_in[13];
    float* out = (float*)d_out;

    // workspace carve-up (~24 MB)
    float* ws     = (float*)d_ws;
    float* states = ws;                       // BB*NN*6
    float* xs0    = states + BB * NN * 6;     // BB*NN*6
    float* xs1    = xs0 + BB * NN * 6;        // BB*NN*HH
    float* xs2    = xs1 + BB * NN * HH;       // BB*NN*HH
    float* dinvp  = xs2 + BB * NN * HH;       // BB*NN
    int*   nbr    = (int*)(dinvp + BB * NN);  // BB*NN*MAXNBR
    int*   cntN   = nbr + BB * NN * MAXNBR;   // BB*NN

    k_init<<<(BB * NN) / 256, 256, 0, stream>>>(points, states, out);
    for (int t = 0; t < PREDL; ++t) {
        k_adj<<<256, 512, 0, stream>>>(states, xs0, dinvp, nbr, cntN);
        k_l0<<<512, 512, 0, stream>>>(xs0, dinvp, nbr, cntN, W0, b0, xs1);
        k_mid<<<512, 512, 0, stream>>>(xs1, dinvp, nbr, cntN, W1, b1, xs2);
        k_last<<<512, 512, 0, stream>>>(xs2, dinvp, nbr, cntN, W2, b2, Wfc, bfc,
                                        padding, states,
                                        out + (size_t)(t + 1) * TSTRIDE);
    }
}